// Round 5
// baseline (372.472 us; speedup 1.0000x reference)
//
#include <hip/hip_runtime.h>
#include <hip/hip_fp16.h>
#include <cmath>

#define DAMPING 0.7f
#define NBUCKETS 32      // 32 buckets x 3125 nodes = 100000
#define NODES_PER_B 3125
#define NPH 1563         // nodes per pass2 half-block (ceil 3125/2)
#define KSLOT 4          // direct-placement bin slots per node (mean 2 recs)
#define OCAP 512         // overflow list capacity (mean ~115/block, ~20 sigma)
#define CHUNK 2048       // edges per pass1 block (3125 blocks)
#define CAP 112          // records per (chunk,bucket); mean 64, +6.1 sigma
#define NCOPIES 32
#define BLOCK 256
#define BLOCK2 512
#define EPT 8            // edges per thread; CHUNK = BLOCK*EPT in ONE shot

// Record: 8 bytes = {x:fp16, y:fp16, z:fp16, li:u16}. Regions array =
// 3125*32*112*8B = 89.6 MB -> mostly IC/L2-resident for pass2 reads.

union h2u {
    __half2 h;
    unsigned u;
};

__device__ __forceinline__ uint2 pack_rec(float ex, float ey, float ez,
                                          int li) {
    h2u lo;
    lo.h = __floats2half2_rn(ex, ey);
    unsigned hi = (unsigned)__half_as_ushort(__float2half_rn(ez)) |
                  ((unsigned)li << 16);
    return make_uint2(lo.u, hi);
}

__device__ __forceinline__ void unpack_add(uint2 r, float& x, float& y,
                                           float& z) {
    h2u lo;
    lo.u = r.x;
    x += __low2float(lo.h);
    y += __high2float(lo.h);
    z += __half2float(__ushort_as_half((unsigned short)(r.y & 0xFFFFu)));
}

// ---------- main path (no global atomics) ----------

// Packed per-node table: cd[i] = {charges[i], polarisability[i]^(1/6)}.
__global__ __launch_bounds__(256) void table_kernel(
    const float* __restrict__ polar, const float* __restrict__ charges,
    float2* __restrict__ cd, int n) {
    int i = blockIdx.x * blockDim.x + threadIdx.x;
    if (i < n) cd[i] = make_float2(charges[i], powf(polar[i], 1.0f / 6.0f));
}

// Pass 1 (v3, unchanged): MLP-first single 8-edge shot per thread.
__global__ __launch_bounds__(256) void pass1_kernel(
    const int* __restrict__ esrc, const int* __restrict__ edst,
    const float* __restrict__ dist, const float* __restrict__ vec,
    const float2* __restrict__ cd, uint2* __restrict__ regions,
    unsigned* __restrict__ counts, int n_edges) {
    __shared__ unsigned gcur[NBUCKETS];
    const int c = blockIdx.x;
    const long base0 = (long)c * CHUNK;
    if (threadIdx.x < NBUCKETS) gcur[threadIdx.x] = 0u;
    __syncthreads();
    uint2* __restrict__ myreg = regions + (long)c * NBUCKETS * CAP;

    const long e0 = base0 + (long)threadIdx.x * EPT;
    if (e0 + EPT <= n_edges) {
        int4 sA = *reinterpret_cast<const int4*>(esrc + e0);
        int4 sB = *reinterpret_cast<const int4*>(esrc + e0 + 4);
        int4 dA = *reinterpret_cast<const int4*>(edst + e0);
        int4 dB = *reinterpret_cast<const int4*>(edst + e0 + 4);
        float4 rA = *reinterpret_cast<const float4*>(dist + e0);
        float4 rB = *reinterpret_cast<const float4*>(dist + e0 + 4);
        float4 v0 = *reinterpret_cast<const float4*>(vec + 3 * e0);
        float4 v1 = *reinterpret_cast<const float4*>(vec + 3 * e0 + 4);
        float4 v2 = *reinterpret_cast<const float4*>(vec + 3 * e0 + 8);
        float4 v3 = *reinterpret_cast<const float4*>(vec + 3 * e0 + 12);
        float4 v4 = *reinterpret_cast<const float4*>(vec + 3 * e0 + 16);
        float4 v5 = *reinterpret_cast<const float4*>(vec + 3 * e0 + 20);
        int s[EPT] = {sA.x, sA.y, sA.z, sA.w, sB.x, sB.y, sB.z, sB.w};
        int d[EPT] = {dA.x, dA.y, dA.z, dA.w, dB.x, dB.y, dB.z, dB.w};
        float r[EPT] = {rA.x, rA.y, rA.z, rA.w, rB.x, rB.y, rB.z, rB.w};
        float v[3 * EPT] = {v0.x, v0.y, v0.z, v0.w, v1.x, v1.y, v1.z, v1.w,
                            v2.x, v2.y, v2.z, v2.w, v3.x, v3.y, v3.z, v3.w,
                            v4.x, v4.y, v4.z, v4.w, v5.x, v5.y, v5.z, v5.w};
        float2 cs[EPT], cdd[EPT];
#pragma unroll
        for (int k = 0; k < EPT; ++k) cs[k] = cd[s[k]];
#pragma unroll
        for (int k = 0; k < EPT; ++k) cdd[k] = cd[d[k]];
        uint2 rec[EPT];
        int b[EPT];
#pragma unroll
        for (int k = 0; k < EPT; ++k) {
            float a6 = cs[k].y * cdd[k].y;
            float rr = r[k];
            float u = rr / a6;
            float damp = 1.0f - __expf(-DAMPING * u * sqrtf(u));
            float coeff = -cdd[k].x * damp / (rr * rr * rr);
            b[k] = s[k] / NODES_PER_B;
            int li = s[k] - b[k] * NODES_PER_B;
            rec[k] = pack_rec(coeff * v[3 * k + 0], coeff * v[3 * k + 1],
                              coeff * v[3 * k + 2], li);
        }
        unsigned slot[EPT];
#pragma unroll
        for (int k = 0; k < EPT; ++k) slot[k] = atomicAdd(&gcur[b[k]], 1u);
#pragma unroll
        for (int k = 0; k < EPT; ++k)
            if (slot[k] < (unsigned)CAP) myreg[b[k] * CAP + slot[k]] = rec[k];
    } else {
        for (long e = e0; e < e0 + EPT && e < n_edges; ++e) {
            int s = esrc[e];
            int d = edst[e];
            float2 cs = cd[s];
            float2 cdd = cd[d];
            float a6 = cs.y * cdd.y;
            float rr = dist[e];
            float u = rr / a6;
            float damp = 1.0f - __expf(-DAMPING * u * sqrtf(u));
            float coeff = -cdd.x * damp / (rr * rr * rr);
            int b = s / NODES_PER_B;
            int li = s - b * NODES_PER_B;
            uint2 rec = pack_rec(coeff * vec[3 * e + 0], coeff * vec[3 * e + 1],
                                 coeff * vec[3 * e + 2], li);
            unsigned slot = atomicAdd(&gcur[b], 1u);
            if (slot < (unsigned)CAP) myreg[b * CAP + slot] = rec;
        }
    }
    __syncthreads();
    if (threadIdx.x < NBUCKETS)
        counts[c * NBUCKETS + threadIdx.x] =
            min(gcur[threadIdx.x], (unsigned)CAP);
}

// Pass 2 (v4): direct-placement sort instead of scatter-accumulate.
// Round-3 counters: 19.2M scattered LDS atomics @ ~3.4 cy/lane-atomic = the
// whole 107us (VALU 4.7%, HBM 7.8%, conflicts 0 -> atomic-unit serialization).
// v4 does ONE ds_add_rtn per record (slot claim in a K=4 bin per node) + a
// plain ds_write_b64; rare overflow (mean 2 recs/node, P(>4)~5%) goes to a
// small list. Each block handles HALF a bucket's nodes (h=0/1) so bins fit
// 64KB LDS; halves re-read the same strips (L2/IC-resident) and write
// disjoint node ranges of plane k. f32 accumulation unchanged -> same absmax.
__global__ __launch_bounds__(512) void pass2_kernel(
    const uint2* __restrict__ regions, const unsigned* __restrict__ counts,
    float* __restrict__ copies, int nchunks, int n_nodes) {
    __shared__ unsigned cnt[NPH];          // 6.25 KB
    __shared__ uint2 sorted[NPH * KSLOT];  // 50.0 KB
    __shared__ uint2 olist[OCAP];          // 4.0 KB
    __shared__ unsigned scounts[128];
    __shared__ unsigned ocur;
    // grid = 32 buckets * 2 halves * 32 copies
    const int b = blockIdx.x >> 6;
    const int h = (blockIdx.x >> 5) & 1;
    const int k = blockIdx.x & 31;
    const int nstrips = (nchunks - k + NCOPIES - 1) / NCOPIES;  // <= 98
    for (int j = threadIdx.x; j < NPH; j += BLOCK2) cnt[j] = 0u;
    if (threadIdx.x == 0) ocur = 0u;
    if (threadIdx.x < nstrips)
        scounts[threadIdx.x] =
            counts[(long)(k + threadIdx.x * NCOPIES) * NBUCKETS + b];
    __syncthreads();
    const int wave = threadIdx.x >> 6;
    const int lane = threadIdx.x & 63;
    const int lo = h * NPH;
    // ---- placement phase: 1 rtn-atomic + 1 plain ds_write per kept record
    for (int j = wave; j < nstrips; j += 8) {
        unsigned n = scounts[j];
        const uint2* rg =
            regions + ((long)(k + j * NCOPIES) * NBUCKETS + b) * CAP;
        for (unsigned i = lane; i < n; i += 64) {
            uint2 r = rg[i];  // coalesced 8B, L2/IC-resident
            int li = (int)(r.y >> 16) - lo;
            if ((unsigned)li < (unsigned)NPH) {
                unsigned slot = atomicAdd(&cnt[li], 1u);
                if (slot < (unsigned)KSLOT) {
                    sorted[li * KSLOT + slot] = r;
                } else {
                    unsigned o = atomicAdd(&ocur, 1u);
                    if (o < (unsigned)OCAP) olist[o] = r;
                }
            }
        }
    }
    __syncthreads();
    // ---- gather phase: register f32 sums, no atomics
    const unsigned no = min(ocur, (unsigned)OCAP);
    float ax[4] = {0.f, 0.f, 0.f, 0.f};
    float ay[4] = {0.f, 0.f, 0.f, 0.f};
    float az[4] = {0.f, 0.f, 0.f, 0.f};
#pragma unroll
    for (int jj = 0; jj < 4; ++jj) {
        int li = (int)threadIdx.x + jj * BLOCK2;
        if (li < NPH) {
            unsigned c = min(cnt[li], (unsigned)KSLOT);
#pragma unroll
            for (unsigned s = 0; s < (unsigned)KSLOT; ++s) {
                if (s < c) {
                    uint2 r = sorted[li * KSLOT + s];
                    unpack_add(r, ax[jj], ay[jj], az[jj]);
                }
            }
        }
    }
    // overflow entries: broadcast LDS reads, unrolled static-index match
    for (unsigned o = 0; o < no; ++o) {
        uint2 r = olist[o];
        int li = (int)(r.y >> 16) - lo;
#pragma unroll
        for (int jj = 0; jj < 4; ++jj) {
            if (li == (int)threadIdx.x + jj * BLOCK2)
                unpack_add(r, ax[jj], ay[jj], az[jj]);
        }
    }
    // ---- write out (contiguous across wave: 12B per lane)
    float* __restrict__ plane = copies + (long)k * (3L * n_nodes);
#pragma unroll
    for (int jj = 0; jj < 4; ++jj) {
        int li = (int)threadIdx.x + jj * BLOCK2;
        int g = lo + li;
        if (li < NPH && g < NODES_PER_B) {
            long base = 3L * ((long)b * NODES_PER_B + g);
            plane[base + 0] = ax[jj];
            plane[base + 1] = ay[jj];
            plane[base + 2] = az[jj];
        }
    }
}

// float4-vectorized reduction over the NCOPIES planes.
__global__ __launch_bounds__(256) void reduce_kernel(
    const float4* __restrict__ copies, float4* __restrict__ out, int total4) {
    int t = blockIdx.x * blockDim.x + threadIdx.x;
    if (t < total4) {
        float4 s = make_float4(0.f, 0.f, 0.f, 0.f);
#pragma unroll
        for (int k = 0; k < NCOPIES; ++k) {
            float4 v = copies[(long)k * total4 + t];
            s.x += v.x; s.y += v.y; s.z += v.z; s.w += v.w;
        }
        out[t] = s;
    }
}

// ---------- fallback: direct global atomics ----------

__global__ __launch_bounds__(256) void edge_scatter_direct_kernel(
    const int* __restrict__ esrc, const int* __restrict__ edst,
    const float* __restrict__ dist, const float* __restrict__ vec,
    const float* __restrict__ charges, const float* __restrict__ polar,
    float* __restrict__ out, int n_edges) {
    int e = blockIdx.x * blockDim.x + threadIdx.x;
    if (e >= n_edges) return;
    float a6 = powf(polar[esrc[e]] * polar[edst[e]], 1.0f / 6.0f);
    float rr = dist[e];
    float u = rr / a6;
    float damp = 1.0f - expf(-DAMPING * u * sqrtf(u));
    float coeff = -charges[edst[e]] * damp / (rr * rr * rr);
    int base = 3 * esrc[e];
    unsafeAtomicAdd(out + base + 0, coeff * vec[3 * (long)e + 0]);
    unsafeAtomicAdd(out + base + 1, coeff * vec[3 * (long)e + 1]);
    unsafeAtomicAdd(out + base + 2, coeff * vec[3 * (long)e + 2]);
}

extern "C" void kernel_launch(void* const* d_in, const int* in_sizes, int n_in,
                              void* d_out, int out_size, void* d_ws, size_t ws_size,
                              hipStream_t stream) {
    const int* edge_src = (const int*)d_in[1];
    const int* edge_dst = (const int*)d_in[2];
    const float* distances = (const float*)d_in[3];
    const float* vec = (const float*)d_in[4];
    const float* charges = (const float*)d_in[5];
    const float* polar = (const float*)d_in[6];
    float* out = (float*)d_out;

    const int n_edges = in_sizes[1];
    const int n_nodes = in_sizes[0];
    const int nchunks = (n_edges + CHUNK - 1) / CHUNK;  // 3125

    auto align = [](size_t x) { return (x + 4095) & ~(size_t)4095; };
    size_t off_cd = 0;
    size_t cd_bytes = align((size_t)n_nodes * sizeof(float2));
    size_t off_counts = off_cd + cd_bytes;
    size_t counts_bytes = align((size_t)nchunks * NBUCKETS * sizeof(unsigned));
    size_t off_regions = off_counts + counts_bytes;
    size_t regions_bytes =
        align((size_t)nchunks * NBUCKETS * CAP * sizeof(uint2));  // 89.6 MB
    size_t off_copies = off_regions + regions_bytes;
    size_t copies_bytes =
        (size_t)NCOPIES * 3 * (size_t)n_nodes * sizeof(float);  // 38.4 MB
    size_t need = off_copies + copies_bytes;                    // ~129 MB

    bool main_path = (n_nodes == NBUCKETS * NODES_PER_B) &&
                     (nchunks * CHUNK >= n_edges) && (ws_size >= need) &&
                     (nchunks <= NCOPIES * 128) && (CHUNK == BLOCK * EPT);

    if (main_path) {
        float2* cd = (float2*)((char*)d_ws + off_cd);
        unsigned* counts = (unsigned*)((char*)d_ws + off_counts);
        uint2* regions = (uint2*)((char*)d_ws + off_regions);
        float* copies = (float*)((char*)d_ws + off_copies);

        table_kernel<<<(n_nodes + BLOCK - 1) / BLOCK, BLOCK, 0, stream>>>(
            polar, charges, cd, n_nodes);
        pass1_kernel<<<nchunks, BLOCK, 0, stream>>>(
            edge_src, edge_dst, distances, vec, cd, regions, counts, n_edges);
        pass2_kernel<<<NBUCKETS * 2 * NCOPIES, BLOCK2, 0, stream>>>(
            regions, counts, copies, nchunks, n_nodes);
        reduce_kernel<<<((3 * n_nodes / 4) + BLOCK - 1) / BLOCK, BLOCK, 0,
                        stream>>>(
            (const float4*)copies, (float4*)out, 3 * n_nodes / 4);
    } else {
        hipMemsetAsync(d_out, 0, (size_t)out_size * sizeof(float), stream);
        edge_scatter_direct_kernel<<<(n_edges + BLOCK - 1) / BLOCK, BLOCK, 0,
                                     stream>>>(
            edge_src, edge_dst, distances, vec, charges, polar, out, n_edges);
    }
}

// Round 6
// 337.141 us; speedup vs baseline: 1.1048x; 1.1048x over previous
//
#include <hip/hip_runtime.h>
#include <hip/hip_fp16.h>
#include <cmath>

#define DAMPING 0.7f
#define NBUCKETS 32      // 32 buckets x 3125 nodes = 100000
#define NODES_PER_B 3125
#define CHUNK 2048       // edges per pass1 block (3125 blocks)
#define CAP 112          // records per (chunk,bucket); mean 64, +6.1 sigma
#define NCOPIES 32
#define BLOCK 256
#define BLOCK2 512
#define EPT 8            // edges per thread; CHUNK = BLOCK*EPT in ONE shot

// Record: 8 bytes = {x:fp16, y:fp16, z:fp16, li:u16}. Regions array =
// 3125*32*112*8B = 89.6 MB -> mostly IC/L2-resident for pass2 reads.

union h2u {
    __half2 h;
    unsigned u;
};

__device__ __forceinline__ uint2 pack_rec(float ex, float ey, float ez,
                                          int li) {
    h2u lo;
    lo.h = __floats2half2_rn(ex, ey);
    unsigned hi = (unsigned)__half_as_ushort(__float2half_rn(ez)) |
                  ((unsigned)li << 16);
    return make_uint2(lo.u, hi);
}

// ---------- main path (no global atomics) ----------

// Packed per-node table: cd[i] = {charges[i], polarisability[i]^(1/6)}.
__global__ __launch_bounds__(256) void table_kernel(
    const float* __restrict__ polar, const float* __restrict__ charges,
    float2* __restrict__ cd, int n) {
    int i = blockIdx.x * blockDim.x + threadIdx.x;
    if (i < n) cd[i] = make_float2(charges[i], powf(polar[i], 1.0f / 6.0f));
}

// Pass 1 (v3, unchanged): MLP-first single 8-edge shot per thread.
__global__ __launch_bounds__(256) void pass1_kernel(
    const int* __restrict__ esrc, const int* __restrict__ edst,
    const float* __restrict__ dist, const float* __restrict__ vec,
    const float2* __restrict__ cd, uint2* __restrict__ regions,
    unsigned* __restrict__ counts, int n_edges) {
    __shared__ unsigned gcur[NBUCKETS];
    const int c = blockIdx.x;
    const long base0 = (long)c * CHUNK;
    if (threadIdx.x < NBUCKETS) gcur[threadIdx.x] = 0u;
    __syncthreads();
    uint2* __restrict__ myreg = regions + (long)c * NBUCKETS * CAP;

    const long e0 = base0 + (long)threadIdx.x * EPT;
    if (e0 + EPT <= n_edges) {
        int4 sA = *reinterpret_cast<const int4*>(esrc + e0);
        int4 sB = *reinterpret_cast<const int4*>(esrc + e0 + 4);
        int4 dA = *reinterpret_cast<const int4*>(edst + e0);
        int4 dB = *reinterpret_cast<const int4*>(edst + e0 + 4);
        float4 rA = *reinterpret_cast<const float4*>(dist + e0);
        float4 rB = *reinterpret_cast<const float4*>(dist + e0 + 4);
        float4 v0 = *reinterpret_cast<const float4*>(vec + 3 * e0);
        float4 v1 = *reinterpret_cast<const float4*>(vec + 3 * e0 + 4);
        float4 v2 = *reinterpret_cast<const float4*>(vec + 3 * e0 + 8);
        float4 v3 = *reinterpret_cast<const float4*>(vec + 3 * e0 + 12);
        float4 v4 = *reinterpret_cast<const float4*>(vec + 3 * e0 + 16);
        float4 v5 = *reinterpret_cast<const float4*>(vec + 3 * e0 + 20);
        int s[EPT] = {sA.x, sA.y, sA.z, sA.w, sB.x, sB.y, sB.z, sB.w};
        int d[EPT] = {dA.x, dA.y, dA.z, dA.w, dB.x, dB.y, dB.z, dB.w};
        float r[EPT] = {rA.x, rA.y, rA.z, rA.w, rB.x, rB.y, rB.z, rB.w};
        float v[3 * EPT] = {v0.x, v0.y, v0.z, v0.w, v1.x, v1.y, v1.z, v1.w,
                            v2.x, v2.y, v2.z, v2.w, v3.x, v3.y, v3.z, v3.w,
                            v4.x, v4.y, v4.z, v4.w, v5.x, v5.y, v5.z, v5.w};
        float2 cs[EPT], cdd[EPT];
#pragma unroll
        for (int k = 0; k < EPT; ++k) cs[k] = cd[s[k]];
#pragma unroll
        for (int k = 0; k < EPT; ++k) cdd[k] = cd[d[k]];
        uint2 rec[EPT];
        int b[EPT];
#pragma unroll
        for (int k = 0; k < EPT; ++k) {
            float a6 = cs[k].y * cdd[k].y;
            float rr = r[k];
            float u = rr / a6;
            float damp = 1.0f - __expf(-DAMPING * u * sqrtf(u));
            float coeff = -cdd[k].x * damp / (rr * rr * rr);
            b[k] = s[k] / NODES_PER_B;
            int li = s[k] - b[k] * NODES_PER_B;
            rec[k] = pack_rec(coeff * v[3 * k + 0], coeff * v[3 * k + 1],
                              coeff * v[3 * k + 2], li);
        }
        unsigned slot[EPT];
#pragma unroll
        for (int k = 0; k < EPT; ++k) slot[k] = atomicAdd(&gcur[b[k]], 1u);
#pragma unroll
        for (int k = 0; k < EPT; ++k)
            if (slot[k] < (unsigned)CAP) myreg[b[k] * CAP + slot[k]] = rec[k];
    } else {
        for (long e = e0; e < e0 + EPT && e < n_edges; ++e) {
            int s = esrc[e];
            int d = edst[e];
            float2 cs = cd[s];
            float2 cdd = cd[d];
            float a6 = cs.y * cdd.y;
            float rr = dist[e];
            float u = rr / a6;
            float damp = 1.0f - __expf(-DAMPING * u * sqrtf(u));
            float coeff = -cdd.x * damp / (rr * rr * rr);
            int b = s / NODES_PER_B;
            int li = s - b * NODES_PER_B;
            uint2 rec = pack_rec(coeff * vec[3 * e + 0], coeff * vec[3 * e + 1],
                                 coeff * vec[3 * e + 2], li);
            unsigned slot = atomicAdd(&gcur[b], 1u);
            if (slot < (unsigned)CAP) myreg[b * CAP + slot] = rec;
        }
    }
    __syncthreads();
    if (threadIdx.x < NBUCKETS)
        counts[c * NBUCKETS + threadIdx.x] =
            min(gcur[threadIdx.x], (unsigned)CAP);
}

// Pass 2 (v5): scatter-accumulate (round-3 structure, 107us known-good)
// with the MLP-first fix. Round-3's VGPR_Count=28 showed the compiler had
// serialized the strip loop to ~1 outstanding region load per wave against
// ~300-600cy IC/L2 latency — the same disease pass1 had at VGPR=24.
// v5 unrolls the strip loop x4: 8 unconditional bounds-safe loads (4 strips
// x 2 half-waves of the <=112-record strip) issued into registers BEFORE
// any consumer, then 24 exec-masked LDS atomics. Same math, same precision.
__global__ __launch_bounds__(512) void pass2_kernel(
    const uint2* __restrict__ regions, const unsigned* __restrict__ counts,
    float* __restrict__ copies, int nchunks, int n_nodes) {
    __shared__ float acc[NODES_PER_B * 3];  // 37.5 KB
    __shared__ unsigned scounts[128];
    const int b = blockIdx.x / NCOPIES;
    const int k = blockIdx.x % NCOPIES;
    const int nstrips = (nchunks - k + NCOPIES - 1) / NCOPIES;  // <= 98
    for (int j = threadIdx.x; j < NODES_PER_B * 3; j += BLOCK2) acc[j] = 0.f;
    if (threadIdx.x < nstrips)
        scounts[threadIdx.x] =
            counts[(long)(k + threadIdx.x * NCOPIES) * NBUCKETS + b];
    __syncthreads();
    const int wave = threadIdx.x >> 6;
    const int lane = threadIdx.x & 63;
    // safe in-bounds fallback indices (strip counts always >=1 here; loads
    // for invalid strips/lanes stay inside the regions allocation and are
    // discarded by the mask)
    const unsigned i0 = (unsigned)lane;
    const unsigned i1 = (unsigned)min(lane + 64, CAP - 1);
    for (int j0 = wave; j0 < nstrips; j0 += 32) {
        // ---- phase A: resolve 4 strips, issue 8 independent loads ----
        uint2 r[8];
        unsigned n[4];
#pragma unroll
        for (int t = 0; t < 4; ++t) {
            int j = j0 + 8 * t;
            int jc = (j < nstrips) ? j : j0;  // clamp to a valid strip
            n[t] = (j < nstrips) ? scounts[jc] : 0u;
            const uint2* rg =
                regions + ((long)(k + (long)jc * NCOPIES) * NBUCKETS + b) * CAP;
            r[2 * t] = rg[i0];
            r[2 * t + 1] = rg[i1];
        }
        // ---- phase B: exec-masked LDS atomics ----
#pragma unroll
        for (int t = 0; t < 4; ++t) {
#pragma unroll
            for (int hh = 0; hh < 2; ++hh) {
                unsigned idx = (unsigned)lane + 64u * hh;
                if (idx < n[t]) {
                    uint2 rr = r[2 * t + hh];
                    h2u lo;
                    lo.u = rr.x;
                    int li = (int)(rr.y >> 16);
                    atomicAdd(&acc[li * 3 + 0], __low2float(lo.h));
                    atomicAdd(&acc[li * 3 + 1], __high2float(lo.h));
                    atomicAdd(&acc[li * 3 + 2],
                              __half2float(__ushort_as_half(
                                  (unsigned short)(rr.y & 0xFFFFu))));
                }
            }
        }
    }
    __syncthreads();
    float* dst = copies + (long)k * (3L * n_nodes) + (long)b * NODES_PER_B * 3;
    for (int j = threadIdx.x; j < NODES_PER_B * 3; j += BLOCK2)
        dst[j] = acc[j];
}

// float4-vectorized reduction over the NCOPIES planes.
__global__ __launch_bounds__(256) void reduce_kernel(
    const float4* __restrict__ copies, float4* __restrict__ out, int total4) {
    int t = blockIdx.x * blockDim.x + threadIdx.x;
    if (t < total4) {
        float4 s = make_float4(0.f, 0.f, 0.f, 0.f);
#pragma unroll
        for (int k = 0; k < NCOPIES; ++k) {
            float4 v = copies[(long)k * total4 + t];
            s.x += v.x; s.y += v.y; s.z += v.z; s.w += v.w;
        }
        out[t] = s;
    }
}

// ---------- fallback: direct global atomics ----------

__global__ __launch_bounds__(256) void edge_scatter_direct_kernel(
    const int* __restrict__ esrc, const int* __restrict__ edst,
    const float* __restrict__ dist, const float* __restrict__ vec,
    const float* __restrict__ charges, const float* __restrict__ polar,
    float* __restrict__ out, int n_edges) {
    int e = blockIdx.x * blockDim.x + threadIdx.x;
    if (e >= n_edges) return;
    float a6 = powf(polar[esrc[e]] * polar[edst[e]], 1.0f / 6.0f);
    float rr = dist[e];
    float u = rr / a6;
    float damp = 1.0f - expf(-DAMPING * u * sqrtf(u));
    float coeff = -charges[edst[e]] * damp / (rr * rr * rr);
    int base = 3 * esrc[e];
    unsafeAtomicAdd(out + base + 0, coeff * vec[3 * (long)e + 0]);
    unsafeAtomicAdd(out + base + 1, coeff * vec[3 * (long)e + 1]);
    unsafeAtomicAdd(out + base + 2, coeff * vec[3 * (long)e + 2]);
}

extern "C" void kernel_launch(void* const* d_in, const int* in_sizes, int n_in,
                              void* d_out, int out_size, void* d_ws, size_t ws_size,
                              hipStream_t stream) {
    const int* edge_src = (const int*)d_in[1];
    const int* edge_dst = (const int*)d_in[2];
    const float* distances = (const float*)d_in[3];
    const float* vec = (const float*)d_in[4];
    const float* charges = (const float*)d_in[5];
    const float* polar = (const float*)d_in[6];
    float* out = (float*)d_out;

    const int n_edges = in_sizes[1];
    const int n_nodes = in_sizes[0];
    const int nchunks = (n_edges + CHUNK - 1) / CHUNK;  // 3125

    auto align = [](size_t x) { return (x + 4095) & ~(size_t)4095; };
    size_t off_cd = 0;
    size_t cd_bytes = align((size_t)n_nodes * sizeof(float2));
    size_t off_counts = off_cd + cd_bytes;
    size_t counts_bytes = align((size_t)nchunks * NBUCKETS * sizeof(unsigned));
    size_t off_regions = off_counts + counts_bytes;
    size_t regions_bytes =
        align((size_t)nchunks * NBUCKETS * CAP * sizeof(uint2));  // 89.6 MB
    size_t off_copies = off_regions + regions_bytes;
    size_t copies_bytes =
        (size_t)NCOPIES * 3 * (size_t)n_nodes * sizeof(float);  // 38.4 MB
    size_t need = off_copies + copies_bytes;                    // ~129 MB

    bool main_path = (n_nodes == NBUCKETS * NODES_PER_B) &&
                     (nchunks * CHUNK >= n_edges) && (ws_size >= need) &&
                     (nchunks <= NCOPIES * 128) && (CHUNK == BLOCK * EPT);

    if (main_path) {
        float2* cd = (float2*)((char*)d_ws + off_cd);
        unsigned* counts = (unsigned*)((char*)d_ws + off_counts);
        uint2* regions = (uint2*)((char*)d_ws + off_regions);
        float* copies = (float*)((char*)d_ws + off_copies);

        table_kernel<<<(n_nodes + BLOCK - 1) / BLOCK, BLOCK, 0, stream>>>(
            polar, charges, cd, n_nodes);
        pass1_kernel<<<nchunks, BLOCK, 0, stream>>>(
            edge_src, edge_dst, distances, vec, cd, regions, counts, n_edges);
        pass2_kernel<<<NBUCKETS * NCOPIES, BLOCK2, 0, stream>>>(
            regions, counts, copies, nchunks, n_nodes);
        reduce_kernel<<<((3 * n_nodes / 4) + BLOCK - 1) / BLOCK, BLOCK, 0,
                        stream>>>(
            (const float4*)copies, (float4*)out, 3 * n_nodes / 4);
    } else {
        hipMemsetAsync(d_out, 0, (size_t)out_size * sizeof(float), stream);
        edge_scatter_direct_kernel<<<(n_edges + BLOCK - 1) / BLOCK, BLOCK, 0,
                                     stream>>>(
            edge_src, edge_dst, distances, vec, charges, polar, out, n_edges);
    }
}

// Round 7
// 291.606 us; speedup vs baseline: 1.2773x; 1.1562x over previous
//
#include <hip/hip_runtime.h>
#include <hip/hip_fp16.h>
#include <cmath>

#define DAMPING 0.7f
#define NBUCKETS 64      // 64 buckets x 1563 nodes >= 100000
#define NPB 1563         // nodes per bucket (li fits u16)
#define KSLOT 3          // direct-placement slots per node (mean 2 recs/node)
#define CHUNK 4096       // edges per pass1 block (1563 blocks)
#define CAP 112          // records per (chunk,bucket); mean 64, +6 sigma
#define NCOPIES 32
#define BLOCK 256
#define BLOCK2 512
#define EPT 8            // edges per thread per tile; CHUNK = 2*BLOCK*EPT

// Record: 8 bytes = {x:fp16, y:fp16, z:fp16, li:u16}. Regions array =
// 1563*64*112*8B = 89.6 MB -> mostly IC/L2-resident for pass2 reads.

union h2u {
    __half2 h;
    unsigned u;
};

__device__ __forceinline__ uint2 pack_rec(float ex, float ey, float ez,
                                          int li) {
    h2u lo;
    lo.h = __floats2half2_rn(ex, ey);
    unsigned hi = (unsigned)__half_as_ushort(__float2half_rn(ez)) |
                  ((unsigned)li << 16);
    return make_uint2(lo.u, hi);
}

__device__ __forceinline__ void unpack(uint2 r, float& x, float& y, float& z) {
    h2u lo;
    lo.u = r.x;
    x = __low2float(lo.h);
    y = __high2float(lo.h);
    z = __half2float(__ushort_as_half((unsigned short)(r.y & 0xFFFFu)));
}

// ---------- main path (no global atomics) ----------

// Packed per-node table: cd[i] = {charges[i], polarisability[i]^(1/6)}.
__global__ __launch_bounds__(256) void table_kernel(
    const float* __restrict__ polar, const float* __restrict__ charges,
    float2* __restrict__ cd, int n) {
    int i = blockIdx.x * blockDim.x + threadIdx.x;
    if (i < n) cd[i] = make_float2(charges[i], powf(polar[i], 1.0f / 6.0f));
}

// Pass 1: MLP-first 8-edge shots (v3 structure), now 2 tiles/block with
// 64 buckets. All coalesced loads + all 16 scattered cd[] gathers issued
// before any consumer; then compute; then LDS slot-claim + 8B region store.
__global__ __launch_bounds__(256) void pass1_kernel(
    const int* __restrict__ esrc, const int* __restrict__ edst,
    const float* __restrict__ dist, const float* __restrict__ vec,
    const float2* __restrict__ cd, uint2* __restrict__ regions,
    unsigned* __restrict__ counts, int n_edges) {
    __shared__ unsigned gcur[NBUCKETS];
    const int c = blockIdx.x;
    const long base0 = (long)c * CHUNK;
    if (threadIdx.x < NBUCKETS) gcur[threadIdx.x] = 0u;
    __syncthreads();
    uint2* __restrict__ myreg = regions + (long)c * NBUCKETS * CAP;

    for (int t0 = 0; t0 < CHUNK; t0 += BLOCK * EPT) {
        const long e0 = base0 + t0 + (long)threadIdx.x * EPT;
        if (e0 + EPT <= n_edges) {
            int4 sA = *reinterpret_cast<const int4*>(esrc + e0);
            int4 sB = *reinterpret_cast<const int4*>(esrc + e0 + 4);
            int4 dA = *reinterpret_cast<const int4*>(edst + e0);
            int4 dB = *reinterpret_cast<const int4*>(edst + e0 + 4);
            float4 rA = *reinterpret_cast<const float4*>(dist + e0);
            float4 rB = *reinterpret_cast<const float4*>(dist + e0 + 4);
            float4 v0 = *reinterpret_cast<const float4*>(vec + 3 * e0);
            float4 v1 = *reinterpret_cast<const float4*>(vec + 3 * e0 + 4);
            float4 v2 = *reinterpret_cast<const float4*>(vec + 3 * e0 + 8);
            float4 v3 = *reinterpret_cast<const float4*>(vec + 3 * e0 + 12);
            float4 v4 = *reinterpret_cast<const float4*>(vec + 3 * e0 + 16);
            float4 v5 = *reinterpret_cast<const float4*>(vec + 3 * e0 + 20);
            int s[EPT] = {sA.x, sA.y, sA.z, sA.w, sB.x, sB.y, sB.z, sB.w};
            int d[EPT] = {dA.x, dA.y, dA.z, dA.w, dB.x, dB.y, dB.z, dB.w};
            float r[EPT] = {rA.x, rA.y, rA.z, rA.w, rB.x, rB.y, rB.z, rB.w};
            float v[3 * EPT] = {v0.x, v0.y, v0.z, v0.w, v1.x, v1.y, v1.z,
                                v1.w, v2.x, v2.y, v2.z, v2.w, v3.x, v3.y,
                                v3.z, v3.w, v4.x, v4.y, v4.z, v4.w, v5.x,
                                v5.y, v5.z, v5.w};
            float2 cs[EPT], cdd[EPT];
#pragma unroll
            for (int k = 0; k < EPT; ++k) cs[k] = cd[s[k]];
#pragma unroll
            for (int k = 0; k < EPT; ++k) cdd[k] = cd[d[k]];
            uint2 rec[EPT];
            int b[EPT];
#pragma unroll
            for (int k = 0; k < EPT; ++k) {
                float a6 = cs[k].y * cdd[k].y;
                float rr = r[k];
                float u = rr / a6;
                float damp = 1.0f - __expf(-DAMPING * u * sqrtf(u));
                float coeff = -cdd[k].x * damp / (rr * rr * rr);
                b[k] = s[k] / NPB;  // constant divide -> magic mul
                int li = s[k] - b[k] * NPB;
                rec[k] = pack_rec(coeff * v[3 * k + 0], coeff * v[3 * k + 1],
                                  coeff * v[3 * k + 2], li);
            }
            unsigned slot[EPT];
#pragma unroll
            for (int k = 0; k < EPT; ++k) slot[k] = atomicAdd(&gcur[b[k]], 1u);
#pragma unroll
            for (int k = 0; k < EPT; ++k)
                if (slot[k] < (unsigned)CAP)
                    myreg[b[k] * CAP + slot[k]] = rec[k];
        } else {
            for (long e = e0; e < e0 + EPT && e < n_edges; ++e) {
                int s = esrc[e];
                int d = edst[e];
                float2 cs = cd[s];
                float2 cdd = cd[d];
                float a6 = cs.y * cdd.y;
                float rr = dist[e];
                float u = rr / a6;
                float damp = 1.0f - __expf(-DAMPING * u * sqrtf(u));
                float coeff = -cdd.x * damp / (rr * rr * rr);
                int b = s / NPB;
                int li = s - b * NPB;
                uint2 rec =
                    pack_rec(coeff * vec[3 * e + 0], coeff * vec[3 * e + 1],
                             coeff * vec[3 * e + 2], li);
                unsigned slot = atomicAdd(&gcur[b], 1u);
                if (slot < (unsigned)CAP) myreg[b * CAP + slot] = rec;
            }
        }
    }
    __syncthreads();
    if (threadIdx.x < NBUCKETS)
        counts[c * NBUCKETS + threadIdx.x] =
            min(gcur[threadIdx.x], (unsigned)CAP);
}

// Pass 2 (v6): direct-placement, round-5 mistakes fixed.
// Model: scattered DS atomics retire ~1 lane/cy (3 insts x 64 lanes x 1170
// groups/CU ~ 94us = the measured pass2, and v5's load-MLP fix was null).
// v6 cuts scattered-atomic lanes/record 3.0 -> ~1.45: one ds_add_rtn slot
// claim + one plain ds_write into TRANSPOSED sorted[slot][li] (gather reads
// are lane-consecutive -> conflict-free, unlike v4's 16-way), overflow
// (~14% at KSLOT=3) goes straight to f32 LDS atomics in accOv (no olist,
// no O(n) broadcast loop). 64 buckets -> block owns a whole bucket: no
// re-read amplification. LDS = 62.8 KB -> 2 blocks/CU.
__global__ __launch_bounds__(512) void pass2_kernel(
    const uint2* __restrict__ regions, const unsigned* __restrict__ counts,
    float* __restrict__ copies, int nchunks, int n_nodes) {
    __shared__ unsigned cnt[NPB];           // 6.25 KB
    __shared__ uint2 sorted[KSLOT * NPB];   // 37.5 KB
    __shared__ float accOv[NPB * 3];        // 18.75 KB
    __shared__ unsigned scounts[64];
    const int b = blockIdx.x >> 5;  // 0..63
    const int k = blockIdx.x & 31;
    const int nstrips = (nchunks - k + NCOPIES - 1) / NCOPIES;  // <= 49
    for (int j = threadIdx.x; j < NPB; j += BLOCK2) cnt[j] = 0u;
    for (int j = threadIdx.x; j < NPB * 3; j += BLOCK2) accOv[j] = 0.f;
    if (threadIdx.x < nstrips)
        scounts[threadIdx.x] =
            counts[(long)(k + threadIdx.x * NCOPIES) * NBUCKETS + b];
    __syncthreads();
    const int wave = threadIdx.x >> 6;
    const int lane = threadIdx.x & 63;
    const unsigned i0 = (unsigned)lane;
    const unsigned i1 = (unsigned)min(lane + 64, CAP - 1);
    for (int j0 = wave; j0 < nstrips; j0 += 32) {
        // phase A: resolve 4 strips, 8 independent region loads in flight
        uint2 r[8];
        unsigned n[4];
#pragma unroll
        for (int t = 0; t < 4; ++t) {
            int j = j0 + 8 * t;
            int jc = (j < nstrips) ? j : j0;
            n[t] = (j < nstrips) ? scounts[jc] : 0u;
            const uint2* rg =
                regions + ((long)(k + (long)jc * NCOPIES) * NBUCKETS + b) * CAP;
            r[2 * t] = rg[i0];
            r[2 * t + 1] = rg[i1];
        }
        // phase B: 1 claim atomic + 1 plain write (or 3 rare overflow adds)
#pragma unroll
        for (int t = 0; t < 4; ++t) {
#pragma unroll
            for (int hh = 0; hh < 2; ++hh) {
                unsigned idx = (unsigned)lane + 64u * hh;
                if (idx < n[t]) {
                    uint2 rr = r[2 * t + hh];
                    int li = (int)(rr.y >> 16);
                    unsigned slot = atomicAdd(&cnt[li], 1u);
                    if (slot < (unsigned)KSLOT) {
                        sorted[slot * NPB + li] = rr;
                    } else {
                        float x, y, z;
                        unpack(rr, x, y, z);
                        atomicAdd(&accOv[li * 3 + 0], x);
                        atomicAdd(&accOv[li * 3 + 1], y);
                        atomicAdd(&accOv[li * 3 + 2], z);
                    }
                }
            }
        }
    }
    __syncthreads();
    // gather: conflict-free lane-consecutive reads, register f32 sums
    float* __restrict__ plane = copies + (long)k * (3L * n_nodes);
#pragma unroll
    for (int jj = 0; jj < 4; ++jj) {
        int li = (int)threadIdx.x + jj * BLOCK2;
        if (li < NPB) {
            float ax = accOv[li * 3 + 0];
            float ay = accOv[li * 3 + 1];
            float az = accOv[li * 3 + 2];
            unsigned c = min(cnt[li], (unsigned)KSLOT);
#pragma unroll
            for (unsigned s = 0; s < (unsigned)KSLOT; ++s) {
                if (s < c) {
                    float x, y, z;
                    unpack(sorted[s * NPB + li], x, y, z);
                    ax += x;
                    ay += y;
                    az += z;
                }
            }
            int g = b * NPB + li;
            if (g < n_nodes) {
                long base = 3L * g;
                plane[base + 0] = ax;
                plane[base + 1] = ay;
                plane[base + 2] = az;
            }
        }
    }
}

// float4-vectorized reduction over the NCOPIES planes.
__global__ __launch_bounds__(256) void reduce_kernel(
    const float4* __restrict__ copies, float4* __restrict__ out, int total4) {
    int t = blockIdx.x * blockDim.x + threadIdx.x;
    if (t < total4) {
        float4 s = make_float4(0.f, 0.f, 0.f, 0.f);
#pragma unroll
        for (int k = 0; k < NCOPIES; ++k) {
            float4 v = copies[(long)k * total4 + t];
            s.x += v.x; s.y += v.y; s.z += v.z; s.w += v.w;
        }
        out[t] = s;
    }
}

// ---------- fallback: direct global atomics ----------

__global__ __launch_bounds__(256) void edge_scatter_direct_kernel(
    const int* __restrict__ esrc, const int* __restrict__ edst,
    const float* __restrict__ dist, const float* __restrict__ vec,
    const float* __restrict__ charges, const float* __restrict__ polar,
    float* __restrict__ out, int n_edges) {
    int e = blockIdx.x * blockDim.x + threadIdx.x;
    if (e >= n_edges) return;
    float a6 = powf(polar[esrc[e]] * polar[edst[e]], 1.0f / 6.0f);
    float rr = dist[e];
    float u = rr / a6;
    float damp = 1.0f - expf(-DAMPING * u * sqrtf(u));
    float coeff = -charges[edst[e]] * damp / (rr * rr * rr);
    int base = 3 * esrc[e];
    unsafeAtomicAdd(out + base + 0, coeff * vec[3 * (long)e + 0]);
    unsafeAtomicAdd(out + base + 1, coeff * vec[3 * (long)e + 1]);
    unsafeAtomicAdd(out + base + 2, coeff * vec[3 * (long)e + 2]);
}

extern "C" void kernel_launch(void* const* d_in, const int* in_sizes, int n_in,
                              void* d_out, int out_size, void* d_ws, size_t ws_size,
                              hipStream_t stream) {
    const int* edge_src = (const int*)d_in[1];
    const int* edge_dst = (const int*)d_in[2];
    const float* distances = (const float*)d_in[3];
    const float* vec = (const float*)d_in[4];
    const float* charges = (const float*)d_in[5];
    const float* polar = (const float*)d_in[6];
    float* out = (float*)d_out;

    const int n_edges = in_sizes[1];
    const int n_nodes = in_sizes[0];
    const int nchunks = (n_edges + CHUNK - 1) / CHUNK;  // 1563

    auto align = [](size_t x) { return (x + 4095) & ~(size_t)4095; };
    size_t off_cd = 0;
    size_t cd_bytes = align((size_t)n_nodes * sizeof(float2));
    size_t off_counts = off_cd + cd_bytes;
    size_t counts_bytes = align((size_t)nchunks * NBUCKETS * sizeof(unsigned));
    size_t off_regions = off_counts + counts_bytes;
    size_t regions_bytes =
        align((size_t)nchunks * NBUCKETS * CAP * sizeof(uint2));  // 89.6 MB
    size_t off_copies = off_regions + regions_bytes;
    size_t copies_bytes =
        (size_t)NCOPIES * 3 * (size_t)n_nodes * sizeof(float);  // 38.4 MB
    size_t need = off_copies + copies_bytes;                    // ~129 MB

    bool main_path = (n_nodes <= NBUCKETS * NPB) &&
                     ((long)nchunks * CHUNK >= n_edges) && (ws_size >= need) &&
                     (nchunks <= NCOPIES * 64) && (CHUNK == 2 * BLOCK * EPT) &&
                     ((3 * n_nodes) % 4 == 0);

    if (main_path) {
        float2* cd = (float2*)((char*)d_ws + off_cd);
        unsigned* counts = (unsigned*)((char*)d_ws + off_counts);
        uint2* regions = (uint2*)((char*)d_ws + off_regions);
        float* copies = (float*)((char*)d_ws + off_copies);

        table_kernel<<<(n_nodes + BLOCK - 1) / BLOCK, BLOCK, 0, stream>>>(
            polar, charges, cd, n_nodes);
        pass1_kernel<<<nchunks, BLOCK, 0, stream>>>(
            edge_src, edge_dst, distances, vec, cd, regions, counts, n_edges);
        pass2_kernel<<<NBUCKETS * NCOPIES, BLOCK2, 0, stream>>>(
            regions, counts, copies, nchunks, n_nodes);
        reduce_kernel<<<((3 * n_nodes / 4) + BLOCK - 1) / BLOCK, BLOCK, 0,
                        stream>>>(
            (const float4*)copies, (float4*)out, 3 * n_nodes / 4);
    } else {
        hipMemsetAsync(d_out, 0, (size_t)out_size * sizeof(float), stream);
        edge_scatter_direct_kernel<<<(n_edges + BLOCK - 1) / BLOCK, BLOCK, 0,
                                     stream>>>(
            edge_src, edge_dst, distances, vec, charges, polar, out, n_edges);
    }
}

// Round 8
// 268.418 us; speedup vs baseline: 1.3877x; 1.0864x over previous
//
#include <hip/hip_runtime.h>
#include <hip/hip_fp16.h>
#include <cmath>

#define DAMPING 0.7f
#define NBUCKETS 64      // 64 buckets x 1563 nodes >= 100000
#define NPB 1563         // nodes per bucket (li fits u16)
#define KSLOT 3          // pass2 direct-placement slots per node (mean 2)
#define CHUNK 4096       // edges per pass1 block (1563 blocks)
#define CAP 112          // records per (chunk,bucket); mean 64, +6 sigma
#define DEPTH 56         // pass1 staging slots/bucket/tile; mean 32, +4.2σ;
                         // overflow goes DIRECT to final slot (correct)
#define NCOPIES 32
#define BLOCK 256
#define BLOCK2 512
#define EPT 8            // edges per thread per tile; CHUNK = 2*BLOCK*EPT

// Record: 8 bytes = {x:fp16, y:fp16, z:fp16, li:u16}. Regions array =
// 1563*64*112*8B = 89.6 MB.

union h2u {
    __half2 h;
    unsigned u;
};

__device__ __forceinline__ uint2 pack_rec(float ex, float ey, float ez,
                                          int li) {
    h2u lo;
    lo.h = __floats2half2_rn(ex, ey);
    unsigned hi = (unsigned)__half_as_ushort(__float2half_rn(ez)) |
                  ((unsigned)li << 16);
    return make_uint2(lo.u, hi);
}

__device__ __forceinline__ void unpack(uint2 r, float& x, float& y, float& z) {
    h2u lo;
    lo.u = r.x;
    x = __low2float(lo.h);
    y = __high2float(lo.h);
    z = __half2float(__ushort_as_half((unsigned short)(r.y & 0xFFFFu)));
}

// ---------- main path (no global atomics) ----------

// Packed per-node table: cd[i] = {charges[i], polarisability[i]^(1/6)}.
__global__ __launch_bounds__(256) void table_kernel(
    const float* __restrict__ polar, const float* __restrict__ charges,
    float2* __restrict__ cd, int n) {
    int i = blockIdx.x * blockDim.x + threadIdx.x;
    if (i < n) cd[i] = make_float2(charges[i], powf(polar[i], 1.0f / 6.0f));
}

// Pass 1 (v7): round-7 regression diagnosis: 64-bucket windows (57KB/block,
// ~80 blocks/XCD in flight) overflow the 4MB per-XCD L2 -> partial-line
// evictions, WRITE_SIZE 65->99MB. Fix A: stage records in LDS per tile,
// flush coalesced full lines (round-0's overflow-correct scheme, DEPTH=56).
// Fix B: VGPR_Count=52 proves the compiler sank the 16 cd[] gathers into
// their consumers (no MLP); sched_barrier(0) pins them hoisted.
__global__ __launch_bounds__(256) void pass1_kernel(
    const int* __restrict__ esrc, const int* __restrict__ edst,
    const float* __restrict__ dist, const float* __restrict__ vec,
    const float2* __restrict__ cd, uint2* __restrict__ regions,
    unsigned* __restrict__ counts, int n_edges) {
    __shared__ uint2 stage[NBUCKETS][DEPTH];  // 28.7 KB
    __shared__ unsigned scnt[NBUCKETS];
    __shared__ unsigned gcur[NBUCKETS];
    const int c = blockIdx.x;
    const long base0 = (long)c * CHUNK;
    if (threadIdx.x < NBUCKETS) {
        scnt[threadIdx.x] = 0u;
        gcur[threadIdx.x] = 0u;
    }
    __syncthreads();
    uint2* __restrict__ myreg = regions + (long)c * NBUCKETS * CAP;

    for (int t0 = 0; t0 < CHUNK; t0 += BLOCK * EPT) {
        const long e0 = base0 + t0 + (long)threadIdx.x * EPT;
        if (e0 + EPT <= n_edges) {
            int4 sA = *reinterpret_cast<const int4*>(esrc + e0);
            int4 sB = *reinterpret_cast<const int4*>(esrc + e0 + 4);
            int4 dA = *reinterpret_cast<const int4*>(edst + e0);
            int4 dB = *reinterpret_cast<const int4*>(edst + e0 + 4);
            float4 rA = *reinterpret_cast<const float4*>(dist + e0);
            float4 rB = *reinterpret_cast<const float4*>(dist + e0 + 4);
            float4 v0 = *reinterpret_cast<const float4*>(vec + 3 * e0);
            float4 v1 = *reinterpret_cast<const float4*>(vec + 3 * e0 + 4);
            float4 v2 = *reinterpret_cast<const float4*>(vec + 3 * e0 + 8);
            float4 v3 = *reinterpret_cast<const float4*>(vec + 3 * e0 + 12);
            float4 v4 = *reinterpret_cast<const float4*>(vec + 3 * e0 + 16);
            float4 v5 = *reinterpret_cast<const float4*>(vec + 3 * e0 + 20);
            int s[EPT] = {sA.x, sA.y, sA.z, sA.w, sB.x, sB.y, sB.z, sB.w};
            int d[EPT] = {dA.x, dA.y, dA.z, dA.w, dB.x, dB.y, dB.z, dB.w};
            float r[EPT] = {rA.x, rA.y, rA.z, rA.w, rB.x, rB.y, rB.z, rB.w};
            float v[3 * EPT] = {v0.x, v0.y, v0.z, v0.w, v1.x, v1.y, v1.z,
                                v1.w, v2.x, v2.y, v2.z, v2.w, v3.x, v3.y,
                                v3.z, v3.w, v4.x, v4.y, v4.z, v4.w, v5.x,
                                v5.y, v5.z, v5.w};
            float2 cs[EPT], cdd[EPT];
#pragma unroll
            for (int k = 0; k < EPT; ++k) cs[k] = cd[s[k]];
#pragma unroll
            for (int k = 0; k < EPT; ++k) cdd[k] = cd[d[k]];
            // keep all 16 gathers issued before any consumer (VGPR check:
            // should rise from 52 to >=90)
            __builtin_amdgcn_sched_barrier(0);
            uint2 rec[EPT];
            int b[EPT];
#pragma unroll
            for (int k = 0; k < EPT; ++k) {
                float a6 = cs[k].y * cdd[k].y;
                float rr = r[k];
                float u = rr / a6;
                float damp = 1.0f - __expf(-DAMPING * u * sqrtf(u));
                float coeff = -cdd[k].x * damp / (rr * rr * rr);
                b[k] = s[k] / NPB;  // constant divide -> magic mul
                int li = s[k] - b[k] * NPB;
                rec[k] = pack_rec(coeff * v[3 * k + 0], coeff * v[3 * k + 1],
                                  coeff * v[3 * k + 2], li);
            }
#pragma unroll
            for (int k = 0; k < EPT; ++k) {
                unsigned slot = atomicAdd(&scnt[b[k]], 1u);
                if (slot < (unsigned)DEPTH) {
                    stage[b[k]][slot] = rec[k];
                } else {  // rare (+4.2σ): straight to final region slot
                    unsigned gd = gcur[b[k]] + slot;
                    if (gd < (unsigned)CAP) myreg[b[k] * CAP + gd] = rec[k];
                }
            }
        } else {
            for (long e = e0; e < e0 + EPT && e < n_edges; ++e) {
                int s = esrc[e];
                int d = edst[e];
                float2 cs = cd[s];
                float2 cdd = cd[d];
                float a6 = cs.y * cdd.y;
                float rr = dist[e];
                float u = rr / a6;
                float damp = 1.0f - __expf(-DAMPING * u * sqrtf(u));
                float coeff = -cdd.x * damp / (rr * rr * rr);
                int b = s / NPB;
                int li = s - b * NPB;
                uint2 rec =
                    pack_rec(coeff * vec[3 * e + 0], coeff * vec[3 * e + 1],
                             coeff * vec[3 * e + 2], li);
                unsigned slot = atomicAdd(&scnt[b], 1u);
                if (slot < (unsigned)DEPTH) {
                    stage[b][slot] = rec;
                } else {
                    unsigned gd = gcur[b] + slot;
                    if (gd < (unsigned)CAP) myreg[b * CAP + gd] = rec;
                }
            }
        }
        __syncthreads();
        // flush: wave w -> buckets [16w, 16w+16); coalesced full-line stores
        {
            const int wave = threadIdx.x >> 6;
            const int lane = threadIdx.x & 63;
#pragma unroll
            for (int rr = 0; rr < 16; ++rr) {
                int b = wave * 16 + rr;
                unsigned full = scnt[b];
                unsigned n = min(full, (unsigned)DEPTH);
                unsigned g = gcur[b];
                uint2* dst = myreg + b * CAP;
                for (unsigned i = lane; i < n; i += 64) {
                    unsigned o = g + i;
                    if (o < (unsigned)CAP) dst[o] = stage[b][i];
                }
                if (lane == 0) {
                    gcur[b] = min(g + full, (unsigned)CAP);
                    scnt[b] = 0u;
                }
            }
        }
        __syncthreads();
    }
    if (threadIdx.x < NBUCKETS)
        counts[c * NBUCKETS + threadIdx.x] = gcur[threadIdx.x];
}

// Pass 2 (v6, unchanged — measured ~35-40us): direct-placement with
// transposed conflict-free sorted[], accOv overflow, whole-bucket blocks.
__global__ __launch_bounds__(512) void pass2_kernel(
    const uint2* __restrict__ regions, const unsigned* __restrict__ counts,
    float* __restrict__ copies, int nchunks, int n_nodes) {
    __shared__ unsigned cnt[NPB];           // 6.25 KB
    __shared__ uint2 sorted[KSLOT * NPB];   // 37.5 KB
    __shared__ float accOv[NPB * 3];        // 18.75 KB
    __shared__ unsigned scounts[64];
    const int b = blockIdx.x >> 5;  // 0..63
    const int k = blockIdx.x & 31;
    const int nstrips = (nchunks - k + NCOPIES - 1) / NCOPIES;  // <= 49
    for (int j = threadIdx.x; j < NPB; j += BLOCK2) cnt[j] = 0u;
    for (int j = threadIdx.x; j < NPB * 3; j += BLOCK2) accOv[j] = 0.f;
    if (threadIdx.x < nstrips)
        scounts[threadIdx.x] =
            counts[(long)(k + threadIdx.x * NCOPIES) * NBUCKETS + b];
    __syncthreads();
    const int wave = threadIdx.x >> 6;
    const int lane = threadIdx.x & 63;
    const unsigned i0 = (unsigned)lane;
    const unsigned i1 = (unsigned)min(lane + 64, CAP - 1);
    for (int j0 = wave; j0 < nstrips; j0 += 32) {
        // phase A: resolve 4 strips, 8 independent region loads in flight
        uint2 r[8];
        unsigned n[4];
#pragma unroll
        for (int t = 0; t < 4; ++t) {
            int j = j0 + 8 * t;
            int jc = (j < nstrips) ? j : j0;
            n[t] = (j < nstrips) ? scounts[jc] : 0u;
            const uint2* rg =
                regions + ((long)(k + (long)jc * NCOPIES) * NBUCKETS + b) * CAP;
            r[2 * t] = rg[i0];
            r[2 * t + 1] = rg[i1];
        }
        // phase B: 1 claim atomic + 1 plain write (or 3 rare overflow adds)
#pragma unroll
        for (int t = 0; t < 4; ++t) {
#pragma unroll
            for (int hh = 0; hh < 2; ++hh) {
                unsigned idx = (unsigned)lane + 64u * hh;
                if (idx < n[t]) {
                    uint2 rr = r[2 * t + hh];
                    int li = (int)(rr.y >> 16);
                    unsigned slot = atomicAdd(&cnt[li], 1u);
                    if (slot < (unsigned)KSLOT) {
                        sorted[slot * NPB + li] = rr;
                    } else {
                        float x, y, z;
                        unpack(rr, x, y, z);
                        atomicAdd(&accOv[li * 3 + 0], x);
                        atomicAdd(&accOv[li * 3 + 1], y);
                        atomicAdd(&accOv[li * 3 + 2], z);
                    }
                }
            }
        }
    }
    __syncthreads();
    // gather: conflict-free lane-consecutive reads, register f32 sums
    float* __restrict__ plane = copies + (long)k * (3L * n_nodes);
#pragma unroll
    for (int jj = 0; jj < 4; ++jj) {
        int li = (int)threadIdx.x + jj * BLOCK2;
        if (li < NPB) {
            float ax = accOv[li * 3 + 0];
            float ay = accOv[li * 3 + 1];
            float az = accOv[li * 3 + 2];
            unsigned c = min(cnt[li], (unsigned)KSLOT);
#pragma unroll
            for (unsigned s = 0; s < (unsigned)KSLOT; ++s) {
                if (s < c) {
                    float x, y, z;
                    unpack(sorted[s * NPB + li], x, y, z);
                    ax += x;
                    ay += y;
                    az += z;
                }
            }
            int g = b * NPB + li;
            if (g < n_nodes) {
                long base = 3L * g;
                plane[base + 0] = ax;
                plane[base + 1] = ay;
                plane[base + 2] = az;
            }
        }
    }
}

// float4-vectorized reduction over the NCOPIES planes.
__global__ __launch_bounds__(256) void reduce_kernel(
    const float4* __restrict__ copies, float4* __restrict__ out, int total4) {
    int t = blockIdx.x * blockDim.x + threadIdx.x;
    if (t < total4) {
        float4 s = make_float4(0.f, 0.f, 0.f, 0.f);
#pragma unroll
        for (int k = 0; k < NCOPIES; ++k) {
            float4 v = copies[(long)k * total4 + t];
            s.x += v.x; s.y += v.y; s.z += v.z; s.w += v.w;
        }
        out[t] = s;
    }
}

// ---------- fallback: direct global atomics ----------

__global__ __launch_bounds__(256) void edge_scatter_direct_kernel(
    const int* __restrict__ esrc, const int* __restrict__ edst,
    const float* __restrict__ dist, const float* __restrict__ vec,
    const float* __restrict__ charges, const float* __restrict__ polar,
    float* __restrict__ out, int n_edges) {
    int e = blockIdx.x * blockDim.x + threadIdx.x;
    if (e >= n_edges) return;
    float a6 = powf(polar[esrc[e]] * polar[edst[e]], 1.0f / 6.0f);
    float rr = dist[e];
    float u = rr / a6;
    float damp = 1.0f - expf(-DAMPING * u * sqrtf(u));
    float coeff = -charges[edst[e]] * damp / (rr * rr * rr);
    int base = 3 * esrc[e];
    unsafeAtomicAdd(out + base + 0, coeff * vec[3 * (long)e + 0]);
    unsafeAtomicAdd(out + base + 1, coeff * vec[3 * (long)e + 1]);
    unsafeAtomicAdd(out + base + 2, coeff * vec[3 * (long)e + 2]);
}

extern "C" void kernel_launch(void* const* d_in, const int* in_sizes, int n_in,
                              void* d_out, int out_size, void* d_ws, size_t ws_size,
                              hipStream_t stream) {
    const int* edge_src = (const int*)d_in[1];
    const int* edge_dst = (const int*)d_in[2];
    const float* distances = (const float*)d_in[3];
    const float* vec = (const float*)d_in[4];
    const float* charges = (const float*)d_in[5];
    const float* polar = (const float*)d_in[6];
    float* out = (float*)d_out;

    const int n_edges = in_sizes[1];
    const int n_nodes = in_sizes[0];
    const int nchunks = (n_edges + CHUNK - 1) / CHUNK;  // 1563

    auto align = [](size_t x) { return (x + 4095) & ~(size_t)4095; };
    size_t off_cd = 0;
    size_t cd_bytes = align((size_t)n_nodes * sizeof(float2));
    size_t off_counts = off_cd + cd_bytes;
    size_t counts_bytes = align((size_t)nchunks * NBUCKETS * sizeof(unsigned));
    size_t off_regions = off_counts + counts_bytes;
    size_t regions_bytes =
        align((size_t)nchunks * NBUCKETS * CAP * sizeof(uint2));  // 89.6 MB
    size_t off_copies = off_regions + regions_bytes;
    size_t copies_bytes =
        (size_t)NCOPIES * 3 * (size_t)n_nodes * sizeof(float);  // 38.4 MB
    size_t need = off_copies + copies_bytes;                    // ~129 MB

    bool main_path = (n_nodes <= NBUCKETS * NPB) &&
                     ((long)nchunks * CHUNK >= n_edges) && (ws_size >= need) &&
                     (nchunks <= NCOPIES * 64) && (CHUNK == 2 * BLOCK * EPT) &&
                     ((3 * n_nodes) % 4 == 0);

    if (main_path) {
        float2* cd = (float2*)((char*)d_ws + off_cd);
        unsigned* counts = (unsigned*)((char*)d_ws + off_counts);
        uint2* regions = (uint2*)((char*)d_ws + off_regions);
        float* copies = (float*)((char*)d_ws + off_copies);

        table_kernel<<<(n_nodes + BLOCK - 1) / BLOCK, BLOCK, 0, stream>>>(
            polar, charges, cd, n_nodes);
        pass1_kernel<<<nchunks, BLOCK, 0, stream>>>(
            edge_src, edge_dst, distances, vec, cd, regions, counts, n_edges);
        pass2_kernel<<<NBUCKETS * NCOPIES, BLOCK2, 0, stream>>>(
            regions, counts, copies, nchunks, n_nodes);
        reduce_kernel<<<((3 * n_nodes / 4) + BLOCK - 1) / BLOCK, BLOCK, 0,
                        stream>>>(
            (const float4*)copies, (float4*)out, 3 * n_nodes / 4);
    } else {
        hipMemsetAsync(d_out, 0, (size_t)out_size * sizeof(float), stream);
        edge_scatter_direct_kernel<<<(n_edges + BLOCK - 1) / BLOCK, BLOCK, 0,
                                     stream>>>(
            edge_src, edge_dst, distances, vec, charges, polar, out, n_edges);
    }
}